// Round 5
// baseline (419.872 us; speedup 1.0000x reference)
//
#include <hip/hip_runtime.h>

// Problem constants (match reference)
#define C_CLASSES 10000
#define K_PROTO   4
#define D_DIM     2048
#define ROWS      (C_CLASSES * K_PROTO)   // 40000
#define D_VEC     (D_DIM / 4)             // 512 float4 per row
#define CPW       4                       // classes per wave
#define NBLOCKS   625                     // 625*4 waves * 4 classes = 10000 classes

typedef float v4f __attribute__((ext_vector_type(4)));

// Kernel 1: persistent streaming. Each wave owns 4 consecutive classes
// (16 rows, 128 KB contiguous). Row-granular double buffer: prefetch row r+1
// (nontemporal) BEFORE computing row r, so every wave keeps a load in flight
// through its entire lifetime, including the per-class reduce tail.
// Per class, the transposed butterfly leaves lane L holding d[class,L&3];
// lanes 0..3 emit one coalesced 16 B store. No softmax work here (tail depth
// ~7) — finalize handles logsumexp over the 160 KB d array.
__global__ __launch_bounds__(256) void dist_kernel(const v4f* __restrict__ proto,
                                                   const v4f* __restrict__ feat,
                                                   float* __restrict__ d_all) {
    const int wave = (blockIdx.x << 2) | (threadIdx.x >> 6);
    const int lane = threadIdx.x & 63;
    const v4f* p0  = proto + (size_t)wave * CPW * K_PROTO * D_VEC;

    // Feature into registers once (cached loads — shared by all waves).
    v4f f[8];
#pragma unroll
    for (int j = 0; j < 8; ++j) f[j] = feat[j * 64 + lane];

    // Double-buffered row pipeline.
    v4f buf[2][8];
#pragma unroll
    for (int j = 0; j < 8; ++j)
        buf[0][j] = __builtin_nontemporal_load(&p0[j * 64 + lane]);

#pragma unroll
    for (int c = 0; c < CPW; ++c) {
        float acc[4];
#pragma unroll
        for (int rr = 0; rr < 4; ++rr) {
            const int rg = c * 4 + rr;          // global row index within wave
            // Prefetch next row before touching current one.
            if (rg + 1 < CPW * 4) {
                const v4f* pn = p0 + (size_t)(rg + 1) * D_VEC;
#pragma unroll
                for (int j = 0; j < 8; ++j)
                    buf[(rg + 1) & 1][j] = __builtin_nontemporal_load(&pn[j * 64 + lane]);
            }
            const v4f* cur = buf[rg & 1];
            float a = 0.0f;
#pragma unroll
            for (int j = 0; j < 8; ++j) {
                const float dx = cur[j].x - f[j].x;
                const float dy = cur[j].y - f[j].y;
                const float dz = cur[j].z - f[j].z;
                const float dw = cur[j].w - f[j].w;
                a += dx * dx + dy * dy + dz * dz + dw * dw;
            }
            acc[rr] = a;
        }

        // Transposed reduce (next class's row-0 load already in flight).
        // Stage 1: sum each acc within 4-lane groups (lane bits 0-1).
#pragma unroll
        for (int m = 1; m <= 2; m <<= 1) {
            acc[0] += __shfl_xor(acc[0], m, 64);
            acc[1] += __shfl_xor(acc[1], m, 64);
            acc[2] += __shfl_xor(acc[2], m, 64);
            acc[3] += __shfl_xor(acc[3], m, 64);
        }
        const int l3 = lane & 3;
        float v = acc[0];
        v = (l3 == 1) ? acc[1] : v;
        v = (l3 == 2) ? acc[2] : v;
        v = (l3 == 3) ? acc[3] : v;
        // Stage 2: sum across the 16 groups (lane bits 2-5).
#pragma unroll
        for (int m = 4; m <= 32; m <<= 1) v += __shfl_xor(v, m, 64);

        // Lane L holds d[class, L&3]; lanes 0..3 write one 16 B chunk.
        if (lane < 4) d_all[(size_t)(wave * CPW + c) * 4 + lane] = v;
    }
}

// Kernel 2: one 1024-thread block; stable logsumexp over 40000 d values
// (160 KB, L2-hot) + label-row epilogue.
__global__ __launch_bounds__(1024) void finalize_kernel(const float4* __restrict__ d4,
                                                        const int* __restrict__ label,
                                                        float* __restrict__ out) {
    __shared__ float sm[20];
    const int tid  = threadIdx.x;
    const int lane = tid & 63;
    const int wid  = tid >> 6;          // 0..15
    const int N4   = ROWS / 4;          // 10000 float4

    // Pass 1: global min of d.
    float m = 3.402823466e38f;
    for (int i = tid; i < N4; i += 1024) {
        const float4 p = d4[i];
        m = fminf(m, fminf(fminf(p.x, p.y), fminf(p.z, p.w)));
    }
#pragma unroll
    for (int off = 1; off < 64; off <<= 1) m = fminf(m, __shfl_xor(m, off, 64));
    if (lane == 0) sm[wid] = m;
    __syncthreads();
    if (tid == 0) {
        float mm = sm[0];
#pragma unroll
        for (int i = 1; i < 16; ++i) mm = fminf(mm, sm[i]);
        sm[16] = mm;
    }
    __syncthreads();
    const float dmin = sm[16];

    // Pass 2: sum exp(dmin - d).
    float acc = 0.0f;
    for (int i = tid; i < N4; i += 1024) {
        const float4 p = d4[i];
        acc += expf(dmin - p.x) + expf(dmin - p.y) +
               expf(dmin - p.z) + expf(dmin - p.w);
    }
#pragma unroll
    for (int off = 1; off < 64; off <<= 1) acc += __shfl_xor(acc, off, 64);
    if (lane == 0) sm[wid] = acc;
    __syncthreads();
    if (tid == 0) {
        float ss = 0.0f;
#pragma unroll
        for (int i = 0; i < 16; ++i) ss += sm[i];
        const float log_one = -dmin + logf(ss);
        const float* d_all = (const float*)d4;
        const int lbl = label[0];
        float p = 0.0f;
#pragma unroll
        for (int k = 0; k < K_PROTO; ++k) p += log_one + d_all[lbl * K_PROTO + k];
        out[0] = p;
    }
}

extern "C" void kernel_launch(void* const* d_in, const int* in_sizes, int n_in,
                              void* d_out, int out_size, void* d_ws, size_t ws_size,
                              hipStream_t stream) {
    const float* feat  = (const float*)d_in[0];   // [2048] f32
    const int*   label = (const int*)d_in[1];     // [1] int32
    const float* proto = (const float*)d_in[2];   // [10000,4,2048] f32
    float* out   = (float*)d_out;                 // [1] f32
    float* d_all = (float*)d_ws;                  // [40000] f32 (160 KB)

    dist_kernel<<<NBLOCKS, 256, 0, stream>>>(
        (const v4f*)proto, (const v4f*)feat, d_all);
    finalize_kernel<<<1, 1024, 0, stream>>>((const float4*)d_all, label, out);
}